// Round 7
// baseline (254.290 us; speedup 1.0000x reference)
//
#include <hip/hip_runtime.h>
#include <math.h>

#define KEHALF_F 7.199822675975274f   // 14.399645351950548 / 2
#define A_ATOMS 1024
#define LOG2E_F 1.4426950408889634f
#define LN2_F   0.6931471805599453f

#if !__has_builtin(__builtin_amdgcn_exp2f)
extern "C" __device__ float __ocml_native_exp2_f32(float);
#endif
#if !__has_builtin(__builtin_amdgcn_logf)
extern "C" __device__ float __ocml_native_log2_f32(float);
#endif

__device__ __forceinline__ float fast_exp2(float x) {   // v_exp_f32 (2^x)
#if __has_builtin(__builtin_amdgcn_exp2f)
    return __builtin_amdgcn_exp2f(x);
#else
    return __ocml_native_exp2_f32(x);
#endif
}
__device__ __forceinline__ float fast_log2(float x) {   // v_log_f32 (log2 x)
#if __has_builtin(__builtin_amdgcn_logf)
    return __builtin_amdgcn_logf(x);
#else
    return __ocml_native_log2_f32(x);
#endif
}
__device__ __forceinline__ float softplus_f(float x) {
    return LN2_F * fast_log2(1.0f + fast_exp2(x * LOG2E_F));
}

// Prekernel: per-atom table tab[i] = (Zf, Zf^sp(apow) * sp(adiv)), once.
__global__ __launch_bounds__(256) void zbl_pre_kernel(
    const int* __restrict__ atomic_numbers,
    const float* __restrict__ p_adiv, const float* __restrict__ p_apow,
    float2* __restrict__ tab, int n)
{
    const int i = blockIdx.x * 256 + threadIdx.x;
    if (i < n) {
        const float sp_apow = softplus_f(p_apow[0]);
        const float sp_adiv = softplus_f(p_adiv[0]);
        float zf = (float)atomic_numbers[i];
        tab[i] = make_float2(zf, fast_exp2(sp_apow * fast_log2(zf)) * sp_adiv);
    }
}

// Main: 512 threads (8 waves), 16 rows/block -> 1024 blocks = 4/CU, all
// resident from t=0. Each wave: rows base+wid and base+wid+8, sequential.
__global__ __launch_bounds__(512, 8) void zbl_main_kernel(
    const int* __restrict__ neighbors,
    const float* __restrict__ neighbor_mask,
    const float* __restrict__ r_ij,
    const float2* __restrict__ tab,
    const float* __restrict__ p_c1, const float* __restrict__ p_c2,
    const float* __restrict__ p_c3, const float* __restrict__ p_c4,
    const float* __restrict__ p_a1, const float* __restrict__ p_a2,
    const float* __restrict__ p_a3, const float* __restrict__ p_a4,
    float* __restrict__ out, int K)
{
    __shared__ float2 zz[A_ATOMS];

    const int tid = threadIdx.x;
    const int block_row_base = blockIdx.x << 4;        // 16 rows per block
    const int b = block_row_base >> 10;                // A_ATOMS == 1024

    // stage precomputed table: 512 threads x 16B = 8KB, no transform
    ((float4*)zz)[tid] = ((const float4*)(tab + ((size_t)b << 10)))[tid];
    __syncthreads();

    // uniform params (cheap, once per block lifetime)
    float c1 = softplus_f(p_c1[0]), c2 = softplus_f(p_c2[0]);
    float c3 = softplus_f(p_c3[0]), c4 = softplus_f(p_c4[0]);
    const float inv_cs = 1.0f / (c1 + c2 + c3 + c4);
    c1 *= inv_cs; c2 *= inv_cs; c3 *= inv_cs; c4 *= inv_cs;
    const float b1 = -softplus_f(p_a1[0]) * LOG2E_F;
    const float b2 = -softplus_f(p_a2[0]) * LOG2E_F;
    const float b3 = -softplus_f(p_a3[0]) * LOG2E_F;
    const float b4 = -softplus_f(p_a4[0]) * LOG2E_F;

    const int wid  = tid >> 6;
    const int lane = tid & 63;

#define ZBL_TERM(J, M, R)                                                   \
    {                                                                       \
        float2 zj = zz[(J)];                                                \
        float ar = (ziy + zj.y) * (M) * (R);                                \
        float fe = c1 * fast_exp2(b1 * ar) + c2 * fast_exp2(b2 * ar)        \
                 + c3 * fast_exp2(b3 * ar) + c4 * fast_exp2(b4 * ar);       \
        acc += fe * __fdividef(zix * zj.x * (M), (R));                      \
    }

    #pragma unroll 1
    for (int p = 0; p < 2; ++p) {
        const int row = block_row_base + wid + (p << 3);

        const float2 zi = zz[row & (A_ATOMS - 1)];
        const float zix = KEHALF_F * zi.x;
        const float ziy = zi.y;

        const size_t base = (size_t)row * K;
        const int f = (int)((4 - (int)(base & 3)) & 3);
        const int ngroups = (K - f) >> 2;              // 255 for K=1023
        const int tailc   = (K - f) & 3;

        const int*   nb = neighbors     + base;
        const float* mk = neighbor_mask + base;
        const float* rr = r_ij          + base;
        const int4*   nb4 = (const int4*)  (nb + f);
        const float4* mk4 = (const float4*)(mk + f);
        const float4* rr4 = (const float4*)(rr + f);

        float acc = 0.0f;

        const int g0 = lane, g1 = lane + 64, g2 = lane + 128, g3 = lane + 192;
        const int g3c  = g3 < ngroups ? g3 : (ngroups - 1);
        const float w3 = g3 < ngroups ? 1.0f : 0.0f;

        int4   j0 = nb4[g0], j1 = nb4[g1], j2 = nb4[g2], j3 = nb4[g3c];
        float4 m0 = mk4[g0], m1 = mk4[g1], m2 = mk4[g2], m3 = mk4[g3c];
        float4 r0 = rr4[g0], r1 = rr4[g1], r2 = rr4[g2], r3 = rr4[g3c];
        m3.x *= w3; m3.y *= w3; m3.z *= w3; m3.w *= w3;

        ZBL_TERM(j0.x, m0.x, r0.x); ZBL_TERM(j0.y, m0.y, r0.y);
        ZBL_TERM(j0.z, m0.z, r0.z); ZBL_TERM(j0.w, m0.w, r0.w);
        ZBL_TERM(j1.x, m1.x, r1.x); ZBL_TERM(j1.y, m1.y, r1.y);
        ZBL_TERM(j1.z, m1.z, r1.z); ZBL_TERM(j1.w, m1.w, r1.w);
        ZBL_TERM(j2.x, m2.x, r2.x); ZBL_TERM(j2.y, m2.y, r2.y);
        ZBL_TERM(j2.z, m2.z, r2.z); ZBL_TERM(j2.w, m2.w, r2.w);
        ZBL_TERM(j3.x, m3.x, r3.x); ZBL_TERM(j3.y, m3.y, r3.y);
        ZBL_TERM(j3.z, m3.z, r3.z); ZBL_TERM(j3.w, m3.w, r3.w);

        int e = -1;
        if (lane < f)              e = lane;                            // front
        else if (lane - f < tailc) e = f + (ngroups << 2) + (lane - f); // tail
        if (e >= 0) {
            int   j = nb[e];
            float m = mk[e];
            float r = rr[e];
            ZBL_TERM(j, m, r);
        }

        #pragma unroll
        for (int off = 32; off > 0; off >>= 1)
            acc += __shfl_down(acc, off, 64);
        if (lane == 0)
            out[row] = acc;
    }
#undef ZBL_TERM
}

extern "C" void kernel_launch(void* const* d_in, const int* in_sizes, int n_in,
                              void* d_out, int out_size, void* d_ws, size_t ws_size,
                              hipStream_t stream) {
    const int*   neighbors      = (const int*)  d_in[0];
    const float* neighbor_mask  = (const float*)d_in[1];
    const int*   atomic_numbers = (const int*)  d_in[2];
    const float* r_ij           = (const float*)d_in[3];

    float*  out = (float*)d_out;
    float2* tab = (float2*)d_ws;

    const int n = in_sizes[2];          // B*A = 16384
    const int K = in_sizes[0] / n;      // 1023

    zbl_pre_kernel<<<(n + 255) / 256, 256, 0, stream>>>(
        atomic_numbers, (const float*)d_in[4], (const float*)d_in[5], tab, n);

    zbl_main_kernel<<<n / 16, 512, 0, stream>>>(
        neighbors, neighbor_mask, r_ij, tab,
        (const float*)d_in[6], (const float*)d_in[7],
        (const float*)d_in[8], (const float*)d_in[9],
        (const float*)d_in[10], (const float*)d_in[11],
        (const float*)d_in[12], (const float*)d_in[13],
        out, K);
}

// Round 10
// 224.013 us; speedup vs baseline: 1.1352x; 1.1352x over previous
//
#include <hip/hip_runtime.h>
#include <math.h>

#define KEHALF_F 7.199822675975274f   // 14.399645351950548 / 2
#define A_ATOMS 1024
#define LOG2E_F 1.4426950408889634f
#define LN2_F   0.6931471805599453f

#if !__has_builtin(__builtin_amdgcn_exp2f)
extern "C" __device__ float __ocml_native_exp2_f32(float);
#endif
#if !__has_builtin(__builtin_amdgcn_logf)
extern "C" __device__ float __ocml_native_log2_f32(float);
#endif

__device__ __forceinline__ float fast_exp2(float x) {   // v_exp_f32
#if __has_builtin(__builtin_amdgcn_exp2f)
    return __builtin_amdgcn_exp2f(x);
#else
    return __ocml_native_exp2_f32(x);
#endif
}
__device__ __forceinline__ float fast_log2(float x) {   // v_log_f32
#if __has_builtin(__builtin_amdgcn_logf)
    return __builtin_amdgcn_logf(x);
#else
    return __ocml_native_log2_f32(x);
#endif
}
__device__ __forceinline__ float fast_rcp(float x) {    // v_rcp_f32
#if __has_builtin(__builtin_amdgcn_rcpf)
    return __builtin_amdgcn_rcpf(x);
#else
    return __frcp_rn(x);
#endif
}
__device__ __forceinline__ float softplus_f(float x) {
    return LN2_F * fast_log2(1.0f + fast_exp2(x * LOG2E_F));
}

// Prekernel: tab[i] = (Zf, Zf^sp(apow) * sp(adiv))
__global__ __launch_bounds__(256) void zbl_pre_kernel(
    const int* __restrict__ atomic_numbers,
    const float* __restrict__ p_adiv, const float* __restrict__ p_apow,
    float2* __restrict__ tab, int n)
{
    const int i = blockIdx.x * 256 + threadIdx.x;
    if (i < n) {
        const float sp_apow = softplus_f(p_apow[0]);
        const float sp_adiv = softplus_f(p_adiv[0]);
        float zf = (float)atomic_numbers[i];
        tab[i] = make_float2(zf, fast_exp2(sp_apow * fast_log2(zf)) * sp_adiv);
    }
}

// Per-row in-flight data: 12 vec4 loads + fixup scalars (~53 VGPR)
struct RowData {
    int4   j0, j1, j2, j3;
    float4 m0, m1, m2, m3;
    float4 r0, r1, r2, r3;
    float  w3;                 // group-3 validity mask
    int    js; float ms, rs;   // front/tail scalar element
    int    row;
};

__device__ __forceinline__ void load_row(
    RowData& d, int row,
    const int* __restrict__ nbg, const float* __restrict__ mkg,
    const float* __restrict__ rrg, int K, int lane)
{
    d.row = row;
    const size_t base = (size_t)row * K;
    const int f = (int)((4 - (int)(base & 3)) & 3);
    const int ngroups = (K - f) >> 2;
    const int tailc   = (K - f) & 3;

    const int*   nb = nbg + base;
    const float* mk = mkg + base;
    const float* rr = rrg + base;
    const int4*   nb4 = (const int4*)  (nb + f);
    const float4* mk4 = (const float4*)(mk + f);
    const float4* rr4 = (const float4*)(rr + f);

    const int g0 = lane, g1 = lane + 64, g2 = lane + 128, g3 = lane + 192;
    const int g3c = g3 < ngroups ? g3 : (ngroups - 1);
    d.w3 = g3 < ngroups ? 1.0f : 0.0f;

    d.j0 = nb4[g0]; d.j1 = nb4[g1]; d.j2 = nb4[g2]; d.j3 = nb4[g3c];
    d.m0 = mk4[g0]; d.m1 = mk4[g1]; d.m2 = mk4[g2]; d.m3 = mk4[g3c];
    d.r0 = rr4[g0]; d.r1 = rr4[g1]; d.r2 = rr4[g2]; d.r3 = rr4[g3c];

    int e = -1;
    if (lane < f)              e = lane;                            // front
    else if (lane - f < tailc) e = f + (ngroups << 2) + (lane - f); // tail
    const int ec = e < 0 ? 0 : e;
    d.js = nb[ec];
    d.rs = rr[ec];
    float msv = mk[ec];
    d.ms = e >= 0 ? msv : 0.0f;
}

__device__ __forceinline__ void compute_row(
    const RowData& d, const float2* zz,
    float c1, float c2, float c3, float c4,
    float b1, float b2, float b3, float b4,
    float* __restrict__ out, int lane)
{
    const float2 zi = zz[d.row & (A_ATOMS - 1)];
    const float zix = KEHALF_F * zi.x;
    const float ziy = zi.y;

    float acc0 = 0.0f, acc1 = 0.0f, acc2 = 0.0f, acc3 = 0.0f;

#define ZBL_TERM(ACC, J, M, R)                                              \
    {                                                                       \
        float2 zj = zz[(J)];                                                \
        float ar = (ziy + zj.y) * (R);           /* mask NOT in exponent */ \
        float fe = c1 * fast_exp2(b1 * ar) + c2 * fast_exp2(b2 * ar)        \
                 + c3 * fast_exp2(b3 * ar) + c4 * fast_exp2(b4 * ar);       \
        ACC += fe * (zix * zj.x * (M)) * fast_rcp(R);                       \
    }

    float4 m3 = d.m3;
    m3.x *= d.w3; m3.y *= d.w3; m3.z *= d.w3; m3.w *= d.w3;

    ZBL_TERM(acc0, d.j0.x, d.m0.x, d.r0.x); ZBL_TERM(acc1, d.j0.y, d.m0.y, d.r0.y);
    ZBL_TERM(acc2, d.j0.z, d.m0.z, d.r0.z); ZBL_TERM(acc3, d.j0.w, d.m0.w, d.r0.w);
    ZBL_TERM(acc0, d.j1.x, d.m1.x, d.r1.x); ZBL_TERM(acc1, d.j1.y, d.m1.y, d.r1.y);
    ZBL_TERM(acc2, d.j1.z, d.m1.z, d.r1.z); ZBL_TERM(acc3, d.j1.w, d.m1.w, d.r1.w);
    ZBL_TERM(acc0, d.j2.x, d.m2.x, d.r2.x); ZBL_TERM(acc1, d.j2.y, d.m2.y, d.r2.y);
    ZBL_TERM(acc2, d.j2.z, d.m2.z, d.r2.z); ZBL_TERM(acc3, d.j2.w, d.m2.w, d.r2.w);
    ZBL_TERM(acc0, d.j3.x, m3.x,   d.r3.x); ZBL_TERM(acc1, d.j3.y, m3.y,   d.r3.y);
    ZBL_TERM(acc2, d.j3.z, m3.z,   d.r3.z); ZBL_TERM(acc3, d.j3.w, m3.w,   d.r3.w);
    ZBL_TERM(acc0, d.js,   d.ms,   d.rs);
#undef ZBL_TERM

    float acc = (acc0 + acc1) + (acc2 + acc3);
    #pragma unroll
    for (int off = 32; off > 0; off >>= 1)
        acc += __shfl_down(acc, off, 64);
    if (lane == 0)
        out[d.row] = acc;
}

// Main: 256 threads, 16 rows/block (4 consecutive rows per wave, software-
// pipelined with a 2-deep row double-buffer) -> 1024 blocks.
__global__ __launch_bounds__(256) void zbl_main_kernel(
    const int* __restrict__ neighbors,
    const float* __restrict__ neighbor_mask,
    const float* __restrict__ r_ij,
    const float2* __restrict__ tab,
    const float* __restrict__ p_c1, const float* __restrict__ p_c2,
    const float* __restrict__ p_c3, const float* __restrict__ p_c4,
    const float* __restrict__ p_a1, const float* __restrict__ p_a2,
    const float* __restrict__ p_a3, const float* __restrict__ p_a4,
    float* __restrict__ out, int K)
{
    __shared__ float2 zz[A_ATOMS];

    const int tid = threadIdx.x;
    const int block_row_base = blockIdx.x << 4;        // 16 rows per block
    const int b = block_row_base >> 10;

    // issue table loads, overlap the param softplus chain with their latency
    const float4* tabf4 = (const float4*)(tab + ((size_t)b << 10));
    float4 t0 = tabf4[tid];
    float4 t1 = tabf4[tid + 256];

    float c1 = softplus_f(p_c1[0]), c2 = softplus_f(p_c2[0]);
    float c3 = softplus_f(p_c3[0]), c4 = softplus_f(p_c4[0]);
    const float inv_cs = 1.0f / (c1 + c2 + c3 + c4);
    c1 *= inv_cs; c2 *= inv_cs; c3 *= inv_cs; c4 *= inv_cs;
    const float b1 = -softplus_f(p_a1[0]) * LOG2E_F;
    const float b2 = -softplus_f(p_a2[0]) * LOG2E_F;
    const float b3 = -softplus_f(p_a3[0]) * LOG2E_F;
    const float b4 = -softplus_f(p_a4[0]) * LOG2E_F;

    ((float4*)zz)[tid]       = t0;
    ((float4*)zz)[tid + 256] = t1;
    __syncthreads();

    const int wid  = tid >> 6;
    const int lane = tid & 63;
    const int r0 = block_row_base + (wid << 2);        // 4 rows per wave

    RowData A, B;
    load_row(A, r0 + 0, neighbors, neighbor_mask, r_ij, K, lane);
    load_row(B, r0 + 1, neighbors, neighbor_mask, r_ij, K, lane);
    compute_row(A, zz, c1, c2, c3, c4, b1, b2, b3, b4, out, lane);
    load_row(A, r0 + 2, neighbors, neighbor_mask, r_ij, K, lane);
    compute_row(B, zz, c1, c2, c3, c4, b1, b2, b3, b4, out, lane);
    load_row(B, r0 + 3, neighbors, neighbor_mask, r_ij, K, lane);
    compute_row(A, zz, c1, c2, c3, c4, b1, b2, b3, b4, out, lane);
    compute_row(B, zz, c1, c2, c3, c4, b1, b2, b3, b4, out, lane);
}

extern "C" void kernel_launch(void* const* d_in, const int* in_sizes, int n_in,
                              void* d_out, int out_size, void* d_ws, size_t ws_size,
                              hipStream_t stream) {
    const int*   neighbors      = (const int*)  d_in[0];
    const float* neighbor_mask  = (const float*)d_in[1];
    const int*   atomic_numbers = (const int*)  d_in[2];
    const float* r_ij           = (const float*)d_in[3];

    float*  out = (float*)d_out;
    float2* tab = (float2*)d_ws;

    const int n = in_sizes[2];          // B*A = 16384
    const int K = in_sizes[0] / n;      // 1023

    zbl_pre_kernel<<<(n + 255) / 256, 256, 0, stream>>>(
        atomic_numbers, (const float*)d_in[4], (const float*)d_in[5], tab, n);

    zbl_main_kernel<<<n / 16, 256, 0, stream>>>(
        neighbors, neighbor_mask, r_ij, tab,
        (const float*)d_in[6], (const float*)d_in[7],
        (const float*)d_in[8], (const float*)d_in[9],
        (const float*)d_in[10], (const float*)d_in[11],
        (const float*)d_in[12], (const float*)d_in[13],
        out, K);
}

// Round 11
// 217.887 us; speedup vs baseline: 1.1671x; 1.0281x over previous
//
#include <hip/hip_runtime.h>
#include <math.h>

#define KEHALF_F 7.199822675975274f   // 14.399645351950548 / 2
#define A_ATOMS 1024
#define LOG2E_F 1.4426950408889634f
#define LN2_F   0.6931471805599453f

#if !__has_builtin(__builtin_amdgcn_exp2f)
extern "C" __device__ float __ocml_native_exp2_f32(float);
#endif
#if !__has_builtin(__builtin_amdgcn_logf)
extern "C" __device__ float __ocml_native_log2_f32(float);
#endif

__device__ __forceinline__ float fast_exp2(float x) {   // v_exp_f32
#if __has_builtin(__builtin_amdgcn_exp2f)
    return __builtin_amdgcn_exp2f(x);
#else
    return __ocml_native_exp2_f32(x);
#endif
}
__device__ __forceinline__ float fast_log2(float x) {   // v_log_f32
#if __has_builtin(__builtin_amdgcn_logf)
    return __builtin_amdgcn_logf(x);
#else
    return __ocml_native_log2_f32(x);
#endif
}
__device__ __forceinline__ float fast_rcp(float x) {    // v_rcp_f32
#if __has_builtin(__builtin_amdgcn_rcpf)
    return __builtin_amdgcn_rcpf(x);
#else
    return __frcp_rn(x);
#endif
}
__device__ __forceinline__ float softplus_f(float x) {
    return LN2_F * fast_log2(1.0f + fast_exp2(x * LOG2E_F));
}

// Prekernel: tab[i] = (Zf, Zf^sp(apow) * sp(adiv))
__global__ __launch_bounds__(256) void zbl_pre_kernel(
    const int* __restrict__ atomic_numbers,
    const float* __restrict__ p_adiv, const float* __restrict__ p_apow,
    float2* __restrict__ tab, int n)
{
    const int i = blockIdx.x * 256 + threadIdx.x;
    if (i < n) {
        const float sp_apow = softplus_f(p_apow[0]);
        const float sp_adiv = softplus_f(p_adiv[0]);
        float zf = (float)atomic_numbers[i];
        tab[i] = make_float2(zf, fast_exp2(sp_apow * fast_log2(zf)) * sp_adiv);
    }
}

// Main: one row per wave, 4 waves per block -> 4096 blocks. NO LDS, no
// barrier: zj gathered directly from global tab (L1/L2-resident, 8KB/batch).
// Straight-line body: 12 streaming vec4 loads + 17 independent gathers in
// flight; __launch_bounds__(256,4) grants a 128-VGPR budget so the
// scheduler keeps them hoisted (round-10 lesson: default heuristic sank
// them at VGPR=52).
__global__ __launch_bounds__(256, 4) void zbl_main_kernel(
    const int* __restrict__ neighbors,
    const float* __restrict__ neighbor_mask,
    const float* __restrict__ r_ij,
    const float2* __restrict__ tab,
    const float* __restrict__ p_c1, const float* __restrict__ p_c2,
    const float* __restrict__ p_c3, const float* __restrict__ p_c4,
    const float* __restrict__ p_a1, const float* __restrict__ p_a2,
    const float* __restrict__ p_a3, const float* __restrict__ p_a4,
    float* __restrict__ out, int K)
{
    const int tid  = threadIdx.x;
    const int lane = tid & 63;
    const int row  = (blockIdx.x << 2) + (tid >> 6);
    const int b    = row >> 10;                    // A_ATOMS == 1024
    const float2* __restrict__ tb = tab + ((size_t)b << 10);

    const size_t base = (size_t)row * K;
    const int f = (int)((4 - (int)(base & 3)) & 3);
    const int ngroups = (K - f) >> 2;              // 255 for K=1023
    const int tailc   = (K - f) & 3;

    const int*   nb = neighbors     + base;
    const float* mk = neighbor_mask + base;
    const float* rr = r_ij          + base;
    const int4*   nb4 = (const int4*)  (nb + f);
    const float4* mk4 = (const float4*)(mk + f);
    const float4* rr4 = (const float4*)(rr + f);

    const int g0 = lane, g1 = lane + 64, g2 = lane + 128, g3 = lane + 192;
    const int g3c  = g3 < ngroups ? g3 : 0;
    const float w3 = g3 < ngroups ? 1.0f : 0.0f;

    // scalar fixup element (front alignment + tail)
    int e = -1;
    if (lane < f)              e = lane;
    else if (lane - f < tailc) e = f + (ngroups << 2) + (lane - f);
    const int ec = e < 0 ? 0 : e;

    // ---- phase 1: all 12 streaming vec4 loads + fixup scalars ----
    int4   j0 = nb4[g0], j1 = nb4[g1], j2 = nb4[g2], j3 = nb4[g3c];
    float4 m0 = mk4[g0], m1 = mk4[g1], m2 = mk4[g2], m3 = mk4[g3c];
    float4 r0 = rr4[g0], r1 = rr4[g1], r2 = rr4[g2], r3 = rr4[g3c];
    int   js = nb[ec];
    float ms = mk[ec];
    float rs = rr[ec];

    // ---- phase 2: 18 independent float2 gathers (dep only on j's) ----
    float2 zi  = tb[row & (A_ATOMS - 1)];
    float2 z00 = tb[j0.x], z01 = tb[j0.y], z02 = tb[j0.z], z03 = tb[j0.w];
    float2 z10 = tb[j1.x], z11 = tb[j1.y], z12 = tb[j1.z], z13 = tb[j1.w];
    float2 z20 = tb[j2.x], z21 = tb[j2.y], z22 = tb[j2.z], z23 = tb[j2.w];
    float2 z30 = tb[j3.x], z31 = tb[j3.y], z32 = tb[j3.z], z33 = tb[j3.w];
    float2 zs  = tb[js];

    // uniform params (overlaps load latency)
    float c1 = softplus_f(p_c1[0]), c2 = softplus_f(p_c2[0]);
    float c3 = softplus_f(p_c3[0]), c4 = softplus_f(p_c4[0]);
    const float inv_cs = 1.0f / (c1 + c2 + c3 + c4);
    c1 *= inv_cs; c2 *= inv_cs; c3 *= inv_cs; c4 *= inv_cs;
    const float b1 = -softplus_f(p_a1[0]) * LOG2E_F;
    const float b2 = -softplus_f(p_a2[0]) * LOG2E_F;
    const float b3 = -softplus_f(p_a3[0]) * LOG2E_F;
    const float b4 = -softplus_f(p_a4[0]) * LOG2E_F;

    const float zix = KEHALF_F * zi.x;
    const float ziy = zi.y;

    // group-3 + fixup masking
    m3.x *= w3; m3.y *= w3; m3.z *= w3; m3.w *= w3;
    if (e < 0) ms = 0.0f;

    float acc0 = 0.0f, acc1 = 0.0f, acc2 = 0.0f, acc3 = 0.0f;

#define ZBL_TERM(ACC, ZJ, M, R)                                             \
    {                                                                       \
        float ar = (ziy + (ZJ).y) * (R);         /* mask NOT in exponent */ \
        float fe = c1 * fast_exp2(b1 * ar) + c2 * fast_exp2(b2 * ar)        \
                 + c3 * fast_exp2(b3 * ar) + c4 * fast_exp2(b4 * ar);       \
        ACC += fe * (zix * (ZJ).x * (M)) * fast_rcp(R);                     \
    }

    ZBL_TERM(acc0, z00, m0.x, r0.x); ZBL_TERM(acc1, z01, m0.y, r0.y);
    ZBL_TERM(acc2, z02, m0.z, r0.z); ZBL_TERM(acc3, z03, m0.w, r0.w);
    ZBL_TERM(acc0, z10, m1.x, r1.x); ZBL_TERM(acc1, z11, m1.y, r1.y);
    ZBL_TERM(acc2, z12, m1.z, r1.z); ZBL_TERM(acc3, z13, m1.w, r1.w);
    ZBL_TERM(acc0, z20, m2.x, r2.x); ZBL_TERM(acc1, z21, m2.y, r2.y);
    ZBL_TERM(acc2, z22, m2.z, r2.z); ZBL_TERM(acc3, z23, m2.w, r2.w);
    ZBL_TERM(acc0, z30, m3.x, r3.x); ZBL_TERM(acc1, z31, m3.y, r3.y);
    ZBL_TERM(acc2, z32, m3.z, r3.z); ZBL_TERM(acc3, z33, m3.w, r3.w);
    ZBL_TERM(acc0, zs,  ms,   rs);
#undef ZBL_TERM

    float acc = (acc0 + acc1) + (acc2 + acc3);
    #pragma unroll
    for (int off = 32; off > 0; off >>= 1)
        acc += __shfl_down(acc, off, 64);
    if (lane == 0)
        out[row] = acc;
}

extern "C" void kernel_launch(void* const* d_in, const int* in_sizes, int n_in,
                              void* d_out, int out_size, void* d_ws, size_t ws_size,
                              hipStream_t stream) {
    const int*   neighbors      = (const int*)  d_in[0];
    const float* neighbor_mask  = (const float*)d_in[1];
    const int*   atomic_numbers = (const int*)  d_in[2];
    const float* r_ij           = (const float*)d_in[3];

    float*  out = (float*)d_out;
    float2* tab = (float2*)d_ws;

    const int n = in_sizes[2];          // B*A = 16384
    const int K = in_sizes[0] / n;      // 1023

    zbl_pre_kernel<<<(n + 255) / 256, 256, 0, stream>>>(
        atomic_numbers, (const float*)d_in[4], (const float*)d_in[5], tab, n);

    zbl_main_kernel<<<n / 4, 256, 0, stream>>>(
        neighbors, neighbor_mask, r_ij, tab,
        (const float*)d_in[6], (const float*)d_in[7],
        (const float*)d_in[8], (const float*)d_in[9],
        (const float*)d_in[10], (const float*)d_in[11],
        (const float*)d_in[12], (const float*)d_in[13],
        out, K);
}